// Round 1
// baseline (4589.729 us; speedup 1.0000x reference)
//
#include <hip/hip_runtime.h>

#define LOG2PI 1.837877f
#define NEG30 -1e30f
#define NLAB 46
#define KK 4
#define LSEQ 512
#define KC 184            // KK*NLAB
#define BLOCK 512
#define SCL_STRIDE 193    // 192+1 pad to break bank conflicts
#define MRG_STRIDE 17     // 16+1 pad

__device__ __forceinline__ float fastrcp(float x) { return __builtin_amdgcn_rcpf(x); }

__global__ __launch_bounds__(BLOCK) void lveg_kernel(
    const int* __restrict__ tokens,
    const float* __restrict__ s_w_tab,
    const float* __restrict__ s_m_tab,
    const float* __restrict__ s_v_tab,
    const float* __restrict__ t_weight,
    const float* __restrict__ t_mu,
    const float* __restrict__ t_var_p,
    float* __restrict__ out)
{
    __shared__ float scl[NLAB * SCL_STRIDE];                  // [p][kc] scores (35.5 KB)
    __shared__ unsigned long long mrg[NLAB * MRG_STRIDE];     // per-parent 16 partial top4 (6.3 KB)
    __shared__ float4 kcp[2][KC];                             // carry: lam2, glam, z2ks, sc (5.9 KB)
    __shared__ float4 emi[NLAB];                              // emission: sw, 1/sv, sm/sv, z2 (0.7 KB)

    const int b = blockIdx.x;
    const int tid = threadIdx.x;

    // ---- phase-A ownership: tid<460 owns child label ac, parent chunk [p0, p0+pc) ----
    const int ac = tid / 10;
    const int aq = tid - ac * 10;
    const int p0 = (aq < 6) ? aq * 5 : 30 + (aq - 6) * 4;
    const int pc = (aq < 6) ? 5 : 4;
    const bool aown = (tid < 460);

    // loop-invariant per-(c,p) constants, held in registers for the whole kernel
    float cl00[5], cl01[5], cl11[5], ce0[5], ce1[5], cid[5], cA[5];
    if (aown) {
#pragma unroll
        for (int j = 0; j < 5; ++j) {
            if (j < pc) {
                int p = p0 + j;
                int cp = ac * NLAB + p;
                float v0 = t_var_p[cp*3+0], v1 = t_var_p[cp*3+1], v2 = t_var_p[cp*3+2];
                float tm0 = t_mu[cp*2+0],  tm1 = t_mu[cp*2+1];
                float S00 = v0*v0 + v1*v1, S01 = v1*v2, S11 = v2*v2;
                float det = S00*S11 - S01*S01;
                float inv = 1.0f / det;
                float l00 = S11*inv, l01 = -S01*inv, l11 = S00*inv;
                float e0 = l00*tm0 + l01*tm1;
                float e1 = l01*tm0 + l11*tm1;
                float q1 = e0*(S00*e0 + S01*e1) + e1*(S01*e0 + S11*e1);
                float zeta1 = -0.5f*(2.0f*LOG2PI + __logf(det) + q1);
                cl00[j]=l00; cl01[j]=l01; cl11[j]=l11; ce0[j]=e0; ce1[j]=e1; cid[j]=inv;
                cA[j] = zeta1 + LOG2PI + t_weight[cp];
            }
        }
    }

    // ---- init carry from emission at position 0 ----
    if (tid < NLAB) {
        int tok0 = tokens[b * LSEQ];
        int c = tid;
        float sw  = s_w_tab[tok0*NLAB + c];
        float sm  = s_m_tab[tok0*NLAB + c];
        float svr = s_v_tab[tok0*NLAB + c];
        float gv = svr*svr;
        float lam2 = 1.0f / gv;
        float glam = sm * lam2;
        float z2 = -0.5f*(LOG2PI + __logf(gv) + sm*glam);
        kcp[0][c] = make_float4(lam2, glam, sw + z2, sw);
        float zpad = NEG30 - 0.5f*LOG2PI;   // rounds to -1e30f, matches ref
#pragma unroll
        for (int k = 1; k < KK; ++k)
            kcp[0][k*NLAB + c] = make_float4(1.0f, 0.0f, zpad, NEG30);
    }
    __syncthreads();

    int cur = 0;
    for (int t = 1; t < LSEQ; ++t) {
        // ---------- Phase A: all candidate scores ----------
        if (aown) {
#pragma unroll
            for (int k = 0; k < KK; ++k) {
                float4 kv = kcp[cur][k*NLAB + ac];
                float lam2 = kv.x, glam = kv.y, z2 = kv.z;
#pragma unroll
                for (int j = 0; j < 5; ++j) {
                    if (j < pc) {
                        float em0 = ce0[j] + glam;
                        float em1 = ce1[j];
                        float dm  = cid[j] + lam2*cl11[j];
                        float Q   = cl11[j]*em0*em0 - 2.0f*cl01[j]*em0*em1
                                  + (cl00[j] + lam2)*em1*em1;
                        float s = cA[j] + z2 + 0.5f*(Q*fastrcp(dm) - __logf(dm));
                        scl[(p0+j)*SCL_STRIDE + k*NLAB + ac] = s;
                    }
                }
            }
        } else if (tid >= 460 && tid < 460 + NLAB) {
            // emission prefetch for this step (consumed in phase C after barriers)
            int p = tid - 460;
            int tok = tokens[b*LSEQ + t];
            float sw  = s_w_tab[tok*NLAB + p];
            float sm  = s_m_tab[tok*NLAB + p];
            float svr = s_v_tab[tok*NLAB + p];
            float sv = svr*svr;
            float rs = 1.0f / sv;
            float eb = sm * rs;
            float ez = -0.5f*(LOG2PI + __logf(sv) + sm*eb);
            emi[p] = make_float4(sw, rs, eb, ez);
        }
        __syncthreads();

        // ---------- Phase B: per-parent partial top-4 (4 threads/parent) ----------
        if (tid < KC) {
            unsigned q = ((unsigned)tid * 1428u) >> 16;   // tid/46
            int p = tid - (int)q*46;
            unsigned long long t0=0ull, t1=0ull, t2=0ull, t3=0ull;
            int base = p*SCL_STRIDE + (int)q*46;
            int kc0 = (int)q*46;
            for (int i = 0; i < 46; ++i) {
                float s = scl[base + i];
                unsigned u = __float_as_uint(s);
                unsigned mask = ((unsigned)((int)u >> 31)) | 0x80000000u;
                unsigned key = u ^ mask;
                unsigned long long pk = ((unsigned long long)key << 32) | (unsigned)(kc0 + i);
                if (pk > t3) {
                    if (pk > t0)      { t3=t2; t2=t1; t1=t0; t0=pk; }
                    else if (pk > t1) { t3=t2; t2=t1; t1=pk; }
                    else if (pk > t2) { t3=t2; t2=pk; }
                    else              { t3=pk; }
                }
            }
            int mb = p*MRG_STRIDE + (int)q*4;
            mrg[mb+0]=t0; mrg[mb+1]=t1; mrg[mb+2]=t2; mrg[mb+3]=t3;
        }
        __syncthreads();

        // ---------- Phase C: merge + survivor recompute + emission product ----------
        if (tid < KC) {
            unsigned jj = ((unsigned)tid * 1428u) >> 16;  // component j
            int p = tid - (int)jj*46;
            unsigned long long t0=0ull, t1=0ull, t2=0ull, t3=0ull;
#pragma unroll
            for (int i = 0; i < 16; ++i) {
                unsigned long long pk = mrg[p*MRG_STRIDE + i];
                if (pk > t3) {
                    if (pk > t0)      { t3=t2; t2=t1; t1=t0; t0=pk; }
                    else if (pk > t1) { t3=t2; t2=t1; t1=pk; }
                    else if (pk > t2) { t3=t2; t2=pk; }
                    else              { t3=pk; }
                }
            }
            unsigned long long sel = (jj==0u)?t0:(jj==1u)?t1:(jj==2u)?t2:t3;
            unsigned kc  = (unsigned)(sel & 0xffffffffull);
            unsigned key = (unsigned)(sel >> 32);
            unsigned u = (key & 0x80000000u) ? (key ^ 0x80000000u) : ~key;
            float score = __uint_as_float(u);
            unsigned k = (kc * 1428u) >> 16;
            int c = (int)kc - (int)k*46;
            int cp = c*NLAB + p;

            // recompute transition constants for the survivor (L1/L2-resident tables)
            float v0 = t_var_p[cp*3+0], v1 = t_var_p[cp*3+1], v2 = t_var_p[cp*3+2];
            float tm0 = t_mu[cp*2+0],  tm1 = t_mu[cp*2+1];
            float S00 = v0*v0 + v1*v1, S01 = v1*v2, S11 = v2*v2;
            float det = S00*S11 - S01*S01;
            float inv = fastrcp(det);
            float l00 = S11*inv, l01 = -S01*inv, l11 = S00*inv;
            float e0 = l00*tm0 + l01*tm1;
            float e1 = l01*tm0 + l11*tm1;

            float4 kv = kcp[cur][kc];
            float lam2 = kv.x, glam = kv.y;
            float em0 = e0 + glam, em1 = e1;
            float dm  = inv + lam2*l11;
            float rdm = fastrcp(dm);
            float lm00 = l00 + lam2;
            float mu2  = rdm*(lm00*em1 - l01*em0);
            float var2 = lm00*rdm;

            float4 ev = emi[p];
            float rv1 = fastrcp(var2);
            float lam = rv1 + ev.y;
            float emm = mu2*rv1 + ev.z;
            float vm  = fastrcp(lam);
            float z1 = -0.5f*(LOG2PI + __logf(var2) + mu2*mu2*rv1);
            float zm = -0.5f*(LOG2PI + __logf(vm) + emm*emm*vm);
            float nsc = score + (z1 + ev.w - zm) + ev.x;
            kcp[cur ^ 1][(int)jj*NLAB + p] = make_float4(lam, emm, nsc + zm, nsc);
        }
        cur ^= 1;
        __syncthreads();
    }

    // ---------- final logsumexp over 184 component scores ----------
    if (tid == 0) {
        float mx = -1e38f;
        for (int i = 0; i < KC; ++i) mx = fmaxf(mx, kcp[cur][i].w);
        float s = 0.0f;
        for (int i = 0; i < KC; ++i) s += expf(kcp[cur][i].w - mx);
        out[b] = mx + logf(s);
    }
}

extern "C" void kernel_launch(void* const* d_in, const int* in_sizes, int n_in,
                              void* d_out, int out_size, void* d_ws, size_t ws_size,
                              hipStream_t stream) {
    const int*   tokens = (const int*)d_in[0];
    const float* sw     = (const float*)d_in[1];
    const float* sm     = (const float*)d_in[2];
    const float* sv     = (const float*)d_in[3];
    const float* tw     = (const float*)d_in[4];
    const float* tmu    = (const float*)d_in[5];
    const float* tvp    = (const float*)d_in[6];
    float* o = (float*)d_out;
    hipLaunchKernelGGL(lveg_kernel, dim3(64), dim3(BLOCK), 0, stream,
                       tokens, sw, sm, sv, tw, tmu, tvp, o);
}

// Round 2
// 2549.104 us; speedup vs baseline: 1.8005x; 1.8005x over previous
//
#include <hip/hip_runtime.h>

#define LOG2PI 1.837877f
#define NLAB 46
#define KK 4
#define LSEQ 512
#define KC 184            // KK*NLAB
#define BLOCK 448         // 368 A-threads + emission wave
#define NA 368            // 46 parents * 8 lanes
#define EMB 384           // emission threads: wave 6, lanes 384..429

__device__ __forceinline__ float fastrcp(float x){ return __builtin_amdgcn_rcpf(x); }
__device__ __forceinline__ unsigned long long maxu(unsigned long long a, unsigned long long b){ return a>b?a:b; }
__device__ __forceinline__ unsigned long long minu(unsigned long long a, unsigned long long b){ return a>b?b:a; }

__global__ __launch_bounds__(BLOCK) void lveg_kernel(
    const int* __restrict__ tokens,
    const float* __restrict__ s_w_tab,
    const float* __restrict__ s_m_tab,
    const float* __restrict__ s_v_tab,
    const float* __restrict__ t_weight,
    const float* __restrict__ t_mu,
    const float* __restrict__ t_var_p,
    float* __restrict__ out)
{
    // LDS: 33.9K + 16.9K + 5.9K + 1.5K = 58.1 KB (1 block/CU; we have 64 blocks on 256 CUs)
    __shared__ float4 tabA[NLAB*NLAB];   // per-(c,p): e0, e1, inv(det), l11   (phase C)
    __shared__ float2 tabB[NLAB*NLAB];   // per-(c,p): l01, l00                (phase C)
    __shared__ float4 kcp[2][KC];        // carry per (k,c): lam2, glam, sc+z2, sc
    __shared__ float4 emi[2][NLAB];      // emission: sw, 1/sv, sm/sv, z2

    const int b = blockIdx.x;
    const int tid = threadIdx.x;
    const int s = tid & 7;               // lane within parent group
    const int p = tid >> 3;              // parent label (valid for tid < NA)
    const int nc    = (s < 6) ? 6 : 5;   // children owned by this lane
    const int cbase = (s < 6) ? s*6 : 36 + (s-6)*5;

    // ---- one-time: phase-C constant tables into LDS ----
    for (int cp = tid; cp < NLAB*NLAB; cp += BLOCK) {
        float v0 = t_var_p[cp*3+0], v1 = t_var_p[cp*3+1], v2 = t_var_p[cp*3+2];
        float tm0 = t_mu[cp*2+0],  tm1 = t_mu[cp*2+1];
        float S00 = v0*v0 + v1*v1, S01 = v1*v2, S11 = v2*v2;
        float det = S00*S11 - S01*S01;
        float inv = 1.0f / det;
        float l00 = S11*inv, l01 = -S01*inv, l11 = S00*inv;
        float e0 = l00*tm0 + l01*tm1;
        float e1 = l01*tm0 + l11*tm1;
        tabA[cp] = make_float4(e0, e1, inv, l11);
        tabB[cp] = make_float2(l01, l00);
    }

    // ---- one-time: phase-A per-(c,p) constants in registers ----
    float rce0[6], rqa[6], rqb[6], rqc[6], rqe[6], rcid[6], rcA[6];
    if (tid < NA) {
#pragma unroll
        for (int ci = 0; ci < 6; ++ci) {
            if (ci < nc) {
                int cp = (cbase + ci)*NLAB + p;
                float v0 = t_var_p[cp*3+0], v1 = t_var_p[cp*3+1], v2 = t_var_p[cp*3+2];
                float tm0 = t_mu[cp*2+0],  tm1 = t_mu[cp*2+1];
                float S00 = v0*v0 + v1*v1, S01 = v1*v2, S11 = v2*v2;
                float det = S00*S11 - S01*S01;
                float inv = 1.0f / det;
                float l00 = S11*inv, l01 = -S01*inv, l11 = S00*inv;
                float e0 = l00*tm0 + l01*tm1;
                float e1 = l01*tm0 + l11*tm1;
                float q1 = e0*(S00*e0 + S01*e1) + e1*(S01*e0 + S11*e1);
                float zeta1 = -0.5f*(2.0f*LOG2PI + __logf(det) + q1);
                rce0[ci] = e0;
                rqa[ci]  = l11;
                rqb[ci]  = 2.0f*l01*e1;
                rqc[ci]  = l00*e1*e1;
                rqe[ci]  = e1*e1;
                rcid[ci] = inv;
                rcA[ci]  = zeta1 + LOG2PI + t_weight[cp];
            } else {
                rce0[ci]=0.f; rqa[ci]=0.f; rqb[ci]=0.f; rqc[ci]=0.f;
                rqe[ci]=0.f; rcid[ci]=1.f; rcA[ci]=0.f;
            }
        }
    }

    // ---- carry init from emission at position 0 ----
    if (tid < NLAB) {
        int tok0 = tokens[b * LSEQ];
        float sw  = s_w_tab[tok0*NLAB + tid];
        float sm  = s_m_tab[tok0*NLAB + tid];
        float svr = s_v_tab[tok0*NLAB + tid];
        float gv = svr*svr;
        float lam2 = 1.0f / gv;
        float glam = sm * lam2;
        float z2 = -0.5f*(LOG2PI + __logf(gv) + sm*glam);
        kcp[0][tid] = make_float4(lam2, glam, sw + z2, sw);
        float zpad = -1e30f - 0.5f*LOG2PI;
#pragma unroll
        for (int k = 1; k < KK; ++k)
            kcp[0][k*NLAB + tid] = make_float4(1.0f, 0.0f, zpad, -1e30f);
    }
    // ---- emission prefetch for t=1 ----
    if (tid >= EMB && tid < EMB + NLAB) {
        int pe = tid - EMB;
        int tok = tokens[b*LSEQ + 1];
        float sw  = s_w_tab[tok*NLAB + pe];
        float sm  = s_m_tab[tok*NLAB + pe];
        float svr = s_v_tab[tok*NLAB + pe];
        float sv = svr*svr;
        float rs = 1.0f / sv;
        float eb = sm * rs;
        float ez = -0.5f*(LOG2PI + __logf(sv) + sm*eb);
        emi[1][pe] = make_float4(sw, rs, eb, ez);
    }
    __syncthreads();

    int cur = 0;
    for (int t = 1; t < LSEQ; ++t) {
        if (tid < NA) {
            // ---- phase A: 24 candidates for parent p, register top-4 ----
            unsigned long long t0=0ull, t1=0ull, t2=0ull, t3=0ull;
#pragma unroll
            for (int ci = 0; ci < 6; ++ci) {
                if (ci < nc) {
                    int c = cbase + ci;
#pragma unroll
                    for (int k = 0; k < KK; ++k) {
                        float4 kv = kcp[cur][k*NLAB + c];    // broadcast across groups
                        float em0 = rce0[ci] + kv.y;
                        float dm  = fmaf(kv.x, rqa[ci], rcid[ci]);
                        float Q   = fmaf(em0, fmaf(rqa[ci], em0, -rqb[ci]),
                                         fmaf(kv.x, rqe[ci], rqc[ci]));
                        float inner = fmaf(Q, fastrcp(dm), -__logf(dm));
                        float sc = fmaf(0.5f, inner, rcA[ci] + kv.z);
                        unsigned u = __float_as_uint(sc);
                        unsigned key = u ^ (((unsigned)((int)u >> 31)) | 0x80000000u);
                        unsigned long long pk =
                            ((unsigned long long)key << 32) | (unsigned)(k*NLAB + c);
                        // sorted-4 insert (desc)
                        unsigned long long m0 = minu(t0, pk); t0 = maxu(t0, pk);
                        unsigned long long m1 = minu(t1, m0); t1 = maxu(t1, m0);
                        unsigned long long m2 = minu(t2, m1); t2 = maxu(t2, m1);
                        t3 = maxu(t3, m2);
                    }
                }
            }
            // ---- 3-stage bitonic merge across the 8-lane group (no barrier) ----
#pragma unroll
            for (int m = 1; m <= 4; m <<= 1) {
                unsigned long long b0 = __shfl_xor(t0, m, 64);
                unsigned long long b1 = __shfl_xor(t1, m, 64);
                unsigned long long b2 = __shfl_xor(t2, m, 64);
                unsigned long long b3 = __shfl_xor(t3, m, 64);
                unsigned long long L0 = maxu(t0, b3), L1 = maxu(t1, b2);
                unsigned long long L2 = maxu(t2, b1), L3 = maxu(t3, b0);
                unsigned long long x;
                x = maxu(L0, L2); L2 = minu(L0, L2); L0 = x;
                x = maxu(L1, L3); L3 = minu(L1, L3); L1 = x;
                x = maxu(L0, L1); L1 = minu(L0, L1); L0 = x;
                x = maxu(L2, L3); L3 = minu(L2, L3); L2 = x;
                t0 = L0; t1 = L1; t2 = L2; t3 = L3;
            }
            // ---- phase C: lanes s<4 process survivor j=s ----
            if (s < 4) {
                unsigned long long sel = t0;
                if (s == 1) sel = t1; else if (s == 2) sel = t2; else if (s == 3) sel = t3;
                unsigned kci = (unsigned)(sel & 0xffffffffull);
                unsigned key = (unsigned)(sel >> 32);
                unsigned uu = (key & 0x80000000u) ? (key ^ 0x80000000u) : ~key;
                float score = __uint_as_float(uu);
                unsigned k = (kci * 1428u) >> 16;
                int c = (int)kci - (int)k*NLAB;
                int cp = c*NLAB + p;
                float4 ta = tabA[cp];
                float2 tb = tabB[cp];
                float4 kv = kcp[cur][kci];
                float lam2 = kv.x, glam = kv.y;
                float em0 = ta.x + glam;
                float em1 = ta.y;
                float dm  = fmaf(lam2, ta.w, ta.z);
                float rdm = fastrcp(dm);
                float lm00 = tb.y + lam2;
                float mu2  = rdm*(lm00*em1 - tb.x*em0);
                float var2 = lm00*rdm;
                float4 ev = emi[cur ^ 1][p];
                float rv1 = fastrcp(var2);
                float lam = rv1 + ev.y;
                float emm = fmaf(mu2, rv1, ev.z);
                float vm  = fastrcp(lam);
                float z1 = -0.5f*(LOG2PI + __logf(var2) + mu2*mu2*rv1);
                float zm = -0.5f*(LOG2PI + __logf(vm) + emm*emm*vm);
                float nsc = score + (z1 + ev.w - zm) + ev.x;
                kcp[cur ^ 1][(int)s*NLAB + p] = make_float4(lam, emm, nsc + zm, nsc);
            }
        } else if (tid >= EMB && tid < EMB + NLAB) {
            // ---- emission prefetch for step t+1 into emi[(t+1)&1] == emi[cur] ----
            if (t + 1 < LSEQ) {
                int pe = tid - EMB;
                int tok = tokens[b*LSEQ + t + 1];
                float sw  = s_w_tab[tok*NLAB + pe];
                float sm  = s_m_tab[tok*NLAB + pe];
                float svr = s_v_tab[tok*NLAB + pe];
                float sv = svr*svr;
                float rs = 1.0f / sv;
                float eb = sm * rs;
                float ez = -0.5f*(LOG2PI + __logf(sv) + sm*eb);
                emi[cur][pe] = make_float4(sw, rs, eb, ez);
            }
        }
        cur ^= 1;
        __syncthreads();   // the ONLY barrier per step
    }

    // ---- final logsumexp over 184 component scores (wave 0) ----
    if (tid < 64) {
        float mx = -1e38f;
        for (int i = tid; i < KC; i += 64) mx = fmaxf(mx, kcp[cur][i].w);
#pragma unroll
        for (int m = 32; m; m >>= 1) mx = fmaxf(mx, __shfl_xor(mx, m, 64));
        float sum = 0.0f;
        for (int i = tid; i < KC; i += 64) sum += __expf(kcp[cur][i].w - mx);
#pragma unroll
        for (int m = 32; m; m >>= 1) sum += __shfl_xor(sum, m, 64);
        if (tid == 0) out[b] = mx + __logf(sum);
    }
}

extern "C" void kernel_launch(void* const* d_in, const int* in_sizes, int n_in,
                              void* d_out, int out_size, void* d_ws, size_t ws_size,
                              hipStream_t stream) {
    const int*   tokens = (const int*)d_in[0];
    const float* sw     = (const float*)d_in[1];
    const float* sm     = (const float*)d_in[2];
    const float* sv     = (const float*)d_in[3];
    const float* tw     = (const float*)d_in[4];
    const float* tmu    = (const float*)d_in[5];
    const float* tvp    = (const float*)d_in[6];
    float* o = (float*)d_out;
    hipLaunchKernelGGL(lveg_kernel, dim3(64), dim3(BLOCK), 0, stream,
                       tokens, sw, sm, sv, tw, tmu, tvp, o);
}

// Round 3
// 1506.926 us; speedup vs baseline: 3.0458x; 1.6916x over previous
//
#include <hip/hip_runtime.h>

#define LOG2PI 1.837877f
#define NLAB 46
#define KK 4
#define LSEQ 512
#define KC 184            // KK*NLAB
#define BLOCK 832         // 736 A-threads + pad + emission wave (768..831)
#define NA 736            // 46 parents * 16 lanes
#define EMB 768

__device__ __forceinline__ float fastrcp(float x){ return __builtin_amdgcn_rcpf(x); }
__device__ __forceinline__ unsigned umx(unsigned a, unsigned b){ return a > b ? a : b; }
__device__ __forceinline__ unsigned umn(unsigned a, unsigned b){ return a < b ? a : b; }

__global__ __launch_bounds__(BLOCK) void lveg_kernel(
    const int* __restrict__ tokens,
    const float* __restrict__ s_w_tab,
    const float* __restrict__ s_m_tab,
    const float* __restrict__ s_v_tab,
    const float* __restrict__ t_weight,
    const float* __restrict__ t_mu,
    const float* __restrict__ t_var_p,
    float* __restrict__ out)
{
    // LDS: 33856 + 16928 + 5888 + 1472 + 2048 = 60192 B
    __shared__ float4 tabA[NLAB*NLAB];   // per-(c,p): e0, e1, invDetS, l11
    __shared__ float2 tabB[NLAB*NLAB];   // per-(c,p): l01, A(=zeta1+LOG2PI+tw)
    __shared__ float4 kcp[2][KC];        // carry per (k,c): lam2, glam, sc+z2, sc
    __shared__ float4 emi[2][NLAB];      // emission: sw, 1/sv, sm/sv, z2
    __shared__ int    tokL[LSEQ];

    const int b = blockIdx.x;
    const int tid = threadIdx.x;
    const int s = tid & 15;              // lane within 16-lane parent group
    const int p = tid >> 4;              // parent label (valid for tid < NA)
    const int nc = (s < 14) ? 3 : 2;     // children owned: c = s + 16*ci

    // ---- one-time: phase-C constant tables into LDS + token preload ----
    for (int cp = tid; cp < NLAB*NLAB; cp += BLOCK) {
        float v0 = t_var_p[cp*3+0], v1 = t_var_p[cp*3+1], v2 = t_var_p[cp*3+2];
        float tm0 = t_mu[cp*2+0],  tm1 = t_mu[cp*2+1];
        float S00 = v0*v0 + v1*v1, S01 = v1*v2, S11 = v2*v2;
        float det = S00*S11 - S01*S01;
        float inv = 1.0f / det;
        float l00 = S11*inv, l01 = -S01*inv, l11 = S00*inv;
        float e0 = l00*tm0 + l01*tm1;
        float e1 = l01*tm0 + l11*tm1;
        float q1 = e0*(S00*e0 + S01*e1) + e1*(S01*e0 + S11*e1);
        float zeta1 = -0.5f*(2.0f*LOG2PI + __logf(det) + q1);
        tabA[cp] = make_float4(e0, e1, inv, l11);
        tabB[cp] = make_float2(l01, zeta1 + LOG2PI + t_weight[cp]);
    }
    for (int i = tid; i < LSEQ; i += BLOCK) tokL[i] = tokens[b*LSEQ + i];

    // ---- one-time: phase-A per-(c,p) constants in registers ----
    float rce0[3], rl11[3], rqb[3], rqc[3], rqe[3], rinv[3], rA[3];
    if (tid < NA) {
#pragma unroll
        for (int ci = 0; ci < 3; ++ci) {
            if (ci < nc) {
                int cp = (s + 16*ci)*NLAB + p;
                float v0 = t_var_p[cp*3+0], v1 = t_var_p[cp*3+1], v2 = t_var_p[cp*3+2];
                float tm0 = t_mu[cp*2+0],  tm1 = t_mu[cp*2+1];
                float S00 = v0*v0 + v1*v1, S01 = v1*v2, S11 = v2*v2;
                float det = S00*S11 - S01*S01;
                float inv = 1.0f / det;
                float l00 = S11*inv, l01 = -S01*inv, l11 = S00*inv;
                float e0 = l00*tm0 + l01*tm1;
                float e1 = l01*tm0 + l11*tm1;
                float q1 = e0*(S00*e0 + S01*e1) + e1*(S01*e0 + S11*e1);
                float zeta1 = -0.5f*(2.0f*LOG2PI + __logf(det) + q1);
                rce0[ci] = e0;
                rl11[ci] = l11;
                rqb[ci]  = 2.0f*l01*e1;
                rqc[ci]  = l00*e1*e1;
                rqe[ci]  = e1*e1;
                rinv[ci] = inv;
                rA[ci]   = zeta1 + LOG2PI + t_weight[cp];
            } else {
                rce0[ci]=0.f; rl11[ci]=0.f; rqb[ci]=0.f; rqc[ci]=0.f;
                rqe[ci]=0.f; rinv[ci]=1.f; rA[ci]=0.f;
            }
        }
    }

    // ---- carry init from emission at position 0 ----
    if (tid < NLAB) {
        int tok0 = tokens[b * LSEQ];
        float sw  = s_w_tab[tok0*NLAB + tid];
        float sm  = s_m_tab[tok0*NLAB + tid];
        float svr = s_v_tab[tok0*NLAB + tid];
        float gv = svr*svr;
        float lam2 = 1.0f / gv;
        float glam = sm * lam2;
        float z2 = -0.5f*(LOG2PI + __logf(gv) + sm*glam);
        kcp[0][tid] = make_float4(lam2, glam, sw + z2, sw);
        float zpad = -1e30f - 0.5f*LOG2PI;
#pragma unroll
        for (int k = 1; k < KK; ++k)
            kcp[0][k*NLAB + tid] = make_float4(1.0f, 0.0f, zpad, -1e30f);
    }
    // ---- emission prefetch for t=1 ----
    if (tid >= EMB && tid < EMB + NLAB) {
        int pe = tid - EMB;
        int tok = tokens[b*LSEQ + 1];
        float sw  = s_w_tab[tok*NLAB + pe];
        float sm  = s_m_tab[tok*NLAB + pe];
        float svr = s_v_tab[tok*NLAB + pe];
        float sv = svr*svr;
        float rs = 1.0f / sv;
        float eb = sm * rs;
        float ez = -0.5f*(LOG2PI + __logf(sv) + sm*eb);
        emi[1][pe] = make_float4(sw, rs, eb, ez);
    }
    __syncthreads();

    int cur = 0;
    for (int t = 1; t < LSEQ; ++t) {
        if (tid < NA) {
            // ---- phase A: 12 candidates for parent p; u32 packed top-4 insert ----
            unsigned t0=0u, t1=0u, t2=0u, t3=0u;
#pragma unroll
            for (int ci = 0; ci < 3; ++ci) {
                if (ci < nc) {
                    int c = s + 16*ci;
#pragma unroll
                    for (int k = 0; k < KK; ++k) {
                        float4 kv = kcp[cur][k*NLAB + c];
                        float em0 = rce0[ci] + kv.y;
                        float dm  = fmaf(kv.x, rl11[ci], rinv[ci]);
                        float Q   = fmaf(em0, fmaf(rl11[ci], em0, -rqb[ci]),
                                         fmaf(kv.x, rqe[ci], rqc[ci]));
                        float sc  = fmaf(0.5f, fmaf(Q, fastrcp(dm), -__logf(dm)),
                                         rA[ci] + kv.z);
                        unsigned u = __float_as_uint(sc);
                        unsigned key = u ^ (((unsigned)((int)u >> 31)) | 0x80000000u);
                        unsigned pk = (key & 0xFFFFFF00u) | (unsigned)(k*NLAB + c);
                        unsigned m0 = umn(t0, pk); t0 = umx(t0, pk);
                        unsigned m1 = umn(t1, m0); t1 = umx(t1, m0);
                        unsigned m2 = umn(t2, m1); t2 = umx(t2, m1);
                        t3 = umx(t3, m2);
                    }
                }
            }
            // ---- 4-stage bitonic merge across the 16-lane group ----
#pragma unroll
            for (int m = 1; m <= 8; m <<= 1) {
                unsigned b0 = __shfl_xor(t0, m, 64);
                unsigned b1 = __shfl_xor(t1, m, 64);
                unsigned b2 = __shfl_xor(t2, m, 64);
                unsigned b3 = __shfl_xor(t3, m, 64);
                unsigned L0 = umx(t0, b3), L1 = umx(t1, b2);
                unsigned L2 = umx(t2, b1), L3 = umx(t3, b0);
                if (m < 8) {   // last stage: set is final, order irrelevant
                    unsigned x;
                    x = umx(L0, L2); L2 = umn(L0, L2); L0 = x;
                    x = umx(L1, L3); L3 = umn(L1, L3); L1 = x;
                    x = umx(L0, L1); L1 = umn(L0, L1); L0 = x;
                    x = umx(L2, L3); L3 = umn(L2, L3); L2 = x;
                }
                t0 = L0; t1 = L1; t2 = L2; t3 = L3;
            }
            // ---- phase C: lanes s<4 recompute survivor s exactly + emission ----
            if (s < 4) {
                unsigned sel = (s==0)?t0 : (s==1)?t1 : (s==2)?t2 : t3;
                unsigned kc = sel & 0xFFu;
                unsigned k  = (kc * 1428u) >> 16;
                int c  = (int)kc - (int)k*NLAB;
                int cp = c*NLAB + p;
                float4 ta = tabA[cp];                 // e0,e1,inv,l11
                float2 tb = tabB[cp];                 // l01, A
                float4 kv = kcp[cur][kc];
                float lam2 = kv.x, glam = kv.y;
                float em0 = ta.x + glam;
                float em1 = ta.y;
                float l01 = tb.x;
                float l00 = fmaf(l01, l01, ta.z) * fastrcp(ta.w);  // (inv+l01^2)/l11
                float dm  = fmaf(lam2, ta.w, ta.z);
                float rdm = fastrcp(dm);
                float lm00 = l00 + lam2;
                float Q = fmaf(em0, fmaf(ta.w, em0, -2.0f*l01*em1), lm00*em1*em1);
                float score = fmaf(0.5f, fmaf(Q, rdm, -__logf(dm)), tb.y + kv.z);
                float mu2  = rdm*(lm00*em1 - l01*em0);
                float var2 = lm00*rdm;
                float4 ev = emi[cur ^ 1][p];
                float rv1 = fastrcp(var2);
                float lam = rv1 + ev.y;
                float emm = fmaf(mu2, rv1, ev.z);
                float vm  = fastrcp(lam);
                float z1 = -0.5f*(LOG2PI + __logf(var2) + mu2*mu2*rv1);
                float zm = -0.5f*(LOG2PI + __logf(vm) + emm*emm*vm);
                float nsc = score + (z1 + ev.w - zm) + ev.x;
                kcp[cur ^ 1][(int)s*NLAB + p] = make_float4(lam, emm, nsc + zm, nsc);
            }
        } else if (tid >= EMB && tid < EMB + NLAB) {
            // ---- emission prefetch for step t+1 into emi[(t+1)&1] == emi[cur] ----
            if (t + 1 < LSEQ) {
                int pe = tid - EMB;
                int tok = tokL[t + 1];
                float sw  = s_w_tab[tok*NLAB + pe];
                float sm  = s_m_tab[tok*NLAB + pe];
                float svr = s_v_tab[tok*NLAB + pe];
                float sv = svr*svr;
                float rs = 1.0f / sv;
                float eb = sm * rs;
                float ez = -0.5f*(LOG2PI + __logf(sv) + sm*eb);
                emi[cur][pe] = make_float4(sw, rs, eb, ez);
            }
        }
        cur ^= 1;
        __syncthreads();   // the ONLY barrier per step
    }

    // ---- final logsumexp over 184 component scores (wave 0) ----
    if (tid < 64) {
        float mx = -1e38f;
        for (int i = tid; i < KC; i += 64) mx = fmaxf(mx, kcp[cur][i].w);
#pragma unroll
        for (int m = 32; m; m >>= 1) mx = fmaxf(mx, __shfl_xor(mx, m, 64));
        float sum = 0.0f;
        for (int i = tid; i < KC; i += 64) sum += __expf(kcp[cur][i].w - mx);
#pragma unroll
        for (int m = 32; m; m >>= 1) sum += __shfl_xor(sum, m, 64);
        if (tid == 0) out[b] = mx + __logf(sum);
    }
}

extern "C" void kernel_launch(void* const* d_in, const int* in_sizes, int n_in,
                              void* d_out, int out_size, void* d_ws, size_t ws_size,
                              hipStream_t stream) {
    const int*   tokens = (const int*)d_in[0];
    const float* sw     = (const float*)d_in[1];
    const float* sm     = (const float*)d_in[2];
    const float* sv     = (const float*)d_in[3];
    const float* tw     = (const float*)d_in[4];
    const float* tmu    = (const float*)d_in[5];
    const float* tvp    = (const float*)d_in[6];
    float* o = (float*)d_out;
    hipLaunchKernelGGL(lveg_kernel, dim3(64), dim3(BLOCK), 0, stream,
                       tokens, sw, sm, sv, tw, tmu, tvp, o);
}

// Round 4
// 1432.344 us; speedup vs baseline: 3.2043x; 1.0521x over previous
//
#include <hip/hip_runtime.h>

#define LOG2PI 1.837877f
#define NLAB 46
#define KK 4
#define LSEQ 512
#define KC 184            // KK*NLAB
#define BLOCK 832         // 736 A-threads + pad + emission wave (768..831)
#define NA 736            // 46 parents * 16 lanes
#define EMB 768

__device__ __forceinline__ float fastrcp(float x){ return __builtin_amdgcn_rcpf(x); }
__device__ __forceinline__ unsigned umx(unsigned a, unsigned b){ return a > b ? a : b; }
__device__ __forceinline__ unsigned umn(unsigned a, unsigned b){ return a < b ? a : b; }
__device__ __forceinline__ unsigned umed3(unsigned a, unsigned b, unsigned c){
    unsigned d;
    asm("v_med3_u32 %0, %1, %2, %3" : "=v"(d) : "v"(a), "v"(b), "v"(c));
    return d;
}
template<int CTRL>
__device__ __forceinline__ unsigned dppq(unsigned v){   // quad_perm lane exchange (VALU pipe)
    return (unsigned)__builtin_amdgcn_mov_dpp((int)v, CTRL, 0xF, 0xF, false);
}
template<int OFF>
__device__ __forceinline__ unsigned swz(unsigned v){    // ds_swizzle xor (LDS pipe)
    return (unsigned)__builtin_amdgcn_ds_swizzle((int)v, OFF);
}
template<int N> struct IC { static constexpr int value = N; };

__global__ __launch_bounds__(BLOCK) void lveg_kernel(
    const int* __restrict__ tokens,
    const float* __restrict__ s_w_tab,
    const float* __restrict__ s_m_tab,
    const float* __restrict__ s_v_tab,
    const float* __restrict__ t_weight,
    const float* __restrict__ t_mu,
    const float* __restrict__ t_var_p,
    float* __restrict__ out)
{
    // hot arrays first (small immediate LDS offsets)
    __shared__ float4 kcp[2][KC];        // carry per (k,c): lam2, glam, sc+z2, sc
    __shared__ float4 emi[2][NLAB];      // emission: sw, 1/sv, sm/sv, z2
    __shared__ int    tokL[LSEQ];
    __shared__ float4 tabA[NLAB*NLAB];   // per-(c,p): e0, e1, invDetS, l11
    __shared__ float2 tabB[NLAB*NLAB];   // per-(c,p): l01, A(=zeta1+LOG2PI+tw)

    const int b = blockIdx.x;
    const int tid = threadIdx.x;
    const int s = tid & 15;              // lane within 16-lane parent group
    const int p = tid >> 4;              // parent label (valid for tid < NA)
    const unsigned vmask2 = (s < 14) ? 0xFFFFFFFFu : 0u;   // ci=2 validity
    const int c2 = (s < 14) ? (s + 32) : 0;                // clamped ci=2 child

    // ---- one-time: phase-C constant tables into LDS + token preload ----
    for (int cp = tid; cp < NLAB*NLAB; cp += BLOCK) {
        float v0 = t_var_p[cp*3+0], v1 = t_var_p[cp*3+1], v2 = t_var_p[cp*3+2];
        float tm0 = t_mu[cp*2+0],  tm1 = t_mu[cp*2+1];
        float S00 = v0*v0 + v1*v1, S01 = v1*v2, S11 = v2*v2;
        float det = S00*S11 - S01*S01;
        float inv = 1.0f / det;
        float l00 = S11*inv, l01 = -S01*inv, l11 = S00*inv;
        float e0 = l00*tm0 + l01*tm1;
        float e1 = l01*tm0 + l11*tm1;
        float q1 = e0*(S00*e0 + S01*e1) + e1*(S01*e0 + S11*e1);
        float zeta1 = -0.5f*(2.0f*LOG2PI + __logf(det) + q1);
        tabA[cp] = make_float4(e0, e1, inv, l11);
        tabB[cp] = make_float2(l01, zeta1 + LOG2PI + t_weight[cp]);
    }
    for (int i = tid; i < LSEQ; i += BLOCK) tokL[i] = tokens[b*LSEQ + i];

    // ---- one-time: phase-A per-(c,p) constants in registers ----
    float rce0[3], rl11[3], rqb[3], rqc[3], rqe[3], rinv[3], rA[3];
    if (tid < NA) {
#pragma unroll
        for (int ci = 0; ci < 3; ++ci) {
            int c = s + 16*ci;
            if (c < NLAB) {
                int cp = c*NLAB + p;
                float v0 = t_var_p[cp*3+0], v1 = t_var_p[cp*3+1], v2 = t_var_p[cp*3+2];
                float tm0 = t_mu[cp*2+0],  tm1 = t_mu[cp*2+1];
                float S00 = v0*v0 + v1*v1, S01 = v1*v2, S11 = v2*v2;
                float det = S00*S11 - S01*S01;
                float inv = 1.0f / det;
                float l00 = S11*inv, l01 = -S01*inv, l11 = S00*inv;
                float e0 = l00*tm0 + l01*tm1;
                float e1 = l01*tm0 + l11*tm1;
                float q1 = e0*(S00*e0 + S01*e1) + e1*(S01*e0 + S11*e1);
                float zeta1 = -0.5f*(2.0f*LOG2PI + __logf(det) + q1);
                rce0[ci] = e0;
                rl11[ci] = l11;
                rqb[ci]  = 2.0f*l01*e1;
                rqc[ci]  = l00*e1*e1;
                rqe[ci]  = e1*e1;
                rinv[ci] = inv;
                rA[ci]   = zeta1 + LOG2PI + t_weight[cp];
            } else {
                rce0[ci]=0.f; rl11[ci]=0.f; rqb[ci]=0.f; rqc[ci]=0.f;
                rqe[ci]=0.f; rinv[ci]=1.f; rA[ci]=0.f;
            }
        }
    }

    // ---- carry init from emission at position 0 ----
    if (tid < NLAB) {
        int tok0 = tokens[b * LSEQ];
        float sw  = s_w_tab[tok0*NLAB + tid];
        float sm  = s_m_tab[tok0*NLAB + tid];
        float svr = s_v_tab[tok0*NLAB + tid];
        float gv = svr*svr;
        float lam2 = 1.0f / gv;
        float glam = sm * lam2;
        float z2 = -0.5f*(LOG2PI + __logf(gv) + sm*glam);
        kcp[0][tid] = make_float4(lam2, glam, sw + z2, sw);
        float zpad = -1e30f - 0.5f*LOG2PI;
#pragma unroll
        for (int k = 1; k < KK; ++k)
            kcp[0][k*NLAB + tid] = make_float4(1.0f, 0.0f, zpad, -1e30f);
    }
    // ---- emission prefetch for t=1 ----
    if (tid >= EMB && tid < EMB + NLAB) {
        int pe = tid - EMB;
        int tok = tokens[b*LSEQ + 1];
        float sw  = s_w_tab[tok*NLAB + pe];
        float sm  = s_m_tab[tok*NLAB + pe];
        float svr = s_v_tab[tok*NLAB + pe];
        float sv = svr*svr;
        float rs = 1.0f / sv;
        float eb = sm * rs;
        float ez = -0.5f*(LOG2PI + __logf(sv) + sm*eb);
        emi[1][pe] = make_float4(sw, rs, eb, ez);
    }
    __syncthreads();

    // ================= the scan: 1 barrier per step =================
    auto stepf = [&](auto CC, int t) {
        constexpr int CUR = decltype(CC)::value;
        if (tid < NA) {
            // ---- preload all 12 carry float4s (immediate LDS offsets) ----
            float4 kv[KK][3];
#pragma unroll
            for (int k = 0; k < KK; ++k) {
                kv[k][0] = kcp[CUR][k*NLAB + s];
                kv[k][1] = kcp[CUR][k*NLAB + s + 16];
                kv[k][2] = kcp[CUR][k*NLAB + c2];
            }
            // ---- phase A: 12 candidates, u32 packed top-4 via med3 insert ----
            unsigned t0=0u, t1=0u, t2=0u, t3=0u;
#pragma unroll
            for (int ci = 0; ci < 3; ++ci) {
#pragma unroll
                for (int k = 0; k < KK; ++k) {
                    float4 kvv = kv[k][ci];
                    float em0 = rce0[ci] + kvv.y;
                    float dm  = fmaf(kvv.x, rl11[ci], rinv[ci]);
                    float Q   = fmaf(em0, fmaf(rl11[ci], em0, -rqb[ci]),
                                     fmaf(kvv.x, rqe[ci], rqc[ci]));
                    float sc  = fmaf(0.5f, fmaf(Q, fastrcp(dm), -__logf(dm)),
                                     rA[ci] + kvv.z);
                    unsigned u = __float_as_uint(sc);
                    unsigned key = u ^ (((unsigned)((int)u >> 31)) | 0x80000000u);
                    unsigned pk = (key & 0xFFFFFF00u) | (unsigned)(k*NLAB + s + 16*ci);
                    if (ci == 2) pk &= vmask2;     // tail lanes: never selectable
                    unsigned n0 = umx(t0, pk);
                    unsigned n1 = umed3(pk, t0, t1);
                    unsigned n2 = umed3(pk, t1, t2);
                    unsigned n3 = umed3(pk, t2, t3);
                    t0=n0; t1=n1; t2=n2; t3=n3;
                }
            }
            // ---- merge across 16-lane group: DPP (m=1,2) + swizzle (m=4,8) ----
#define MSTAGE(F) { unsigned b0=F(t0), b1=F(t1), b2=F(t2), b3=F(t3);              \
                unsigned L0=umx(t0,b3), L1=umx(t1,b2), L2=umx(t2,b1), L3=umx(t3,b0); \
                unsigned x;                                                       \
                x=umx(L0,L2); L2=umn(L0,L2); L0=x;  x=umx(L1,L3); L3=umn(L1,L3); L1=x; \
                x=umx(L0,L1); L1=umn(L0,L1); L0=x;  x=umx(L2,L3); L3=umn(L2,L3); L2=x; \
                t0=L0; t1=L1; t2=L2; t3=L3; }
            MSTAGE(dppq<0xB1>)      // xor 1 (quad_perm [1,0,3,2])
            MSTAGE(dppq<0x4E>)      // xor 2 (quad_perm [2,3,0,1])
            MSTAGE(swz<0x101F>)     // xor 4
            {   // final stage (xor 8): set-only, no cleanup
                unsigned b0=swz<0x201F>(t0), b1=swz<0x201F>(t1),
                         b2=swz<0x201F>(t2), b3=swz<0x201F>(t3);
                unsigned L0=umx(t0,b3), L1=umx(t1,b2), L2=umx(t2,b1), L3=umx(t3,b0);
                t0=L0; t1=L1; t2=L2; t3=L3;
            }
#undef MSTAGE
            // ---- phase C: lanes s<4 recompute survivor s exactly + emission ----
            if (s < 4) {
                unsigned sel = (s==0)?t0 : (s==1)?t1 : (s==2)?t2 : t3;
                unsigned kc = sel & 0xFFu;
                unsigned k  = (kc * 1428u) >> 16;
                int c  = (int)kc - (int)k*NLAB;
                int cp = c*NLAB + p;
                float4 ta = tabA[cp];                 // e0,e1,inv,l11
                float2 tb = tabB[cp];                 // l01, A
                float4 kvv = kcp[CUR][kc];
                float lam2 = kvv.x, glam = kvv.y;
                float em0 = ta.x + glam;
                float em1 = ta.y;
                float l01 = tb.x;
                float l00 = fmaf(l01, l01, ta.z) * fastrcp(ta.w);  // (inv+l01^2)/l11
                float dm  = fmaf(lam2, ta.w, ta.z);
                float rdm = fastrcp(dm);
                float lm00 = l00 + lam2;
                float Q = fmaf(em0, fmaf(ta.w, em0, -2.0f*l01*em1), lm00*em1*em1);
                float score = fmaf(0.5f, fmaf(Q, rdm, -__logf(dm)), tb.y + kvv.z);
                float mu2  = rdm*(lm00*em1 - l01*em0);
                float var2 = lm00*rdm;
                float4 ev = emi[CUR ^ 1][p];
                float rv1 = fastrcp(var2);
                float lam = rv1 + ev.y;
                float emm = fmaf(mu2, rv1, ev.z);
                float vm  = fastrcp(lam);
                float z1 = -0.5f*(LOG2PI + __logf(var2) + mu2*mu2*rv1);
                float zm = -0.5f*(LOG2PI + __logf(vm) + emm*emm*vm);
                float nsc = score + (z1 + ev.w - zm) + ev.x;
                kcp[CUR ^ 1][(int)s*NLAB + p] = make_float4(lam, emm, nsc + zm, nsc);
            }
        } else if (tid >= EMB && tid < EMB + NLAB) {
            // ---- emission prefetch for step t+1 into emi[CUR] ----
            if (t + 1 < LSEQ) {
                int pe = tid - EMB;
                int tok = tokL[t + 1];
                float sw  = s_w_tab[tok*NLAB + pe];
                float sm  = s_m_tab[tok*NLAB + pe];
                float svr = s_v_tab[tok*NLAB + pe];
                float sv = svr*svr;
                float rs = 1.0f / sv;
                float eb = sm * rs;
                float ez = -0.5f*(LOG2PI + __logf(sv) + sm*eb);
                emi[CUR][pe] = make_float4(sw, rs, eb, ez);
            }
        }
        __syncthreads();   // the ONLY barrier per step
    };

    int t = 1;
#pragma unroll 1
    for (int it = 0; it < (LSEQ - 2) / 2; ++it) {   // 255 double-steps: t=1..510
        stepf(IC<0>{}, t); ++t;
        stepf(IC<1>{}, t); ++t;
    }
    stepf(IC<0>{}, t);   // t = 511; final carry lands in kcp[1]

    // ---- final logsumexp over 184 component scores (wave 0) ----
    if (tid < 64) {
        float mx = -1e38f;
        for (int i = tid; i < KC; i += 64) mx = fmaxf(mx, kcp[1][i].w);
#pragma unroll
        for (int m = 32; m; m >>= 1) mx = fmaxf(mx, __shfl_xor(mx, m, 64));
        float sum = 0.0f;
        for (int i = tid; i < KC; i += 64) sum += __expf(kcp[1][i].w - mx);
#pragma unroll
        for (int m = 32; m; m >>= 1) sum += __shfl_xor(sum, m, 64);
        if (tid == 0) out[b] = mx + __logf(sum);
    }
}

extern "C" void kernel_launch(void* const* d_in, const int* in_sizes, int n_in,
                              void* d_out, int out_size, void* d_ws, size_t ws_size,
                              hipStream_t stream) {
    const int*   tokens = (const int*)d_in[0];
    const float* sw     = (const float*)d_in[1];
    const float* sm     = (const float*)d_in[2];
    const float* sv     = (const float*)d_in[3];
    const float* tw     = (const float*)d_in[4];
    const float* tmu    = (const float*)d_in[5];
    const float* tvp    = (const float*)d_in[6];
    float* o = (float*)d_out;
    hipLaunchKernelGGL(lveg_kernel, dim3(64), dim3(BLOCK), 0, stream,
                       tokens, sw, sm, sv, tw, tmu, tvp, o);
}